// Round 2
// baseline (427.963 us; speedup 1.0000x reference)
//
#include <hip/hip_runtime.h>

constexpr int B = 4, L = 1024, H = 768, NH = 12;
constexpr int E = 32, MPE = 4, K = 16, EM = E * MPE;     // EM=128
constexpr int TYPE_DIM = 20;
constexpr int NNODE = E + EM + K;                         // 176
constexpr int NROWS = NNODE + E + EM;                     // 336
constexpr int F = H + TYPE_DIM;                           // 788

// ---------------------------------------------------------------------------
// Kernel 1: per (b, entity): compute 4 mention head-mean attention rows +
// entity row (mean of the 4) + inverse normalizers. grid = B*E, block = 256.
// Each thread owns 4 consecutive columns (float4 loads).
// ---------------------------------------------------------------------------
__global__ __launch_bounds__(256) void k_rows(
        const float* __restrict__ att, const int* __restrict__ mpos,
        float* __restrict__ m_row, float* __restrict__ e_row,
        float* __restrict__ minv, float* __restrict__ einv) {
    int be = blockIdx.x;            // b*E + e
    int b = be >> 5;
    int tid = threadIdx.x;
    int c0 = tid * 4;

    int pos[MPE];
    float acc[MPE][4];
#pragma unroll
    for (int mp = 0; mp < MPE; ++mp) {
        pos[mp] = mpos[be * MPE + mp] + 1;
#pragma unroll
        for (int j = 0; j < 4; ++j) acc[mp][j] = 0.f;
    }
    for (int nh = 0; nh < NH; ++nh) {
#pragma unroll
        for (int mp = 0; mp < MPE; ++mp) {
            const float* row =
                att + (((size_t)(b * NH + nh)) * L + pos[mp]) * L + c0;
            float4 v = *(const float4*)row;
            acc[mp][0] += v.x; acc[mp][1] += v.y;
            acc[mp][2] += v.z; acc[mp][3] += v.w;
        }
    }
    float part[MPE];
    float er[4] = {0.f, 0.f, 0.f, 0.f};
#pragma unroll
    for (int mp = 0; mp < MPE; ++mp) {
        float s = 0.f;
        float4 w;
        float vals[4];
#pragma unroll
        for (int j = 0; j < 4; ++j) {
            float val = acc[mp][j] * (1.f / NH);
            vals[j] = val; s += val; er[j] += val;
        }
        w.x = vals[0]; w.y = vals[1]; w.z = vals[2]; w.w = vals[3];
        *(float4*)(m_row + ((size_t)(be * MPE + mp)) * L + c0) = w;
        part[mp] = s;
    }
    {
        float4 w; w.x = 0.25f * er[0]; w.y = 0.25f * er[1];
        w.z = 0.25f * er[2]; w.w = 0.25f * er[3];
        *(float4*)(e_row + (size_t)be * L + c0) = w;
    }
    // block-reduce the 4 per-mention sums
    __shared__ float red[4][4];   // [wave][mp]
    __shared__ float ssum[4];
    int lane = tid & 63, wid = tid >> 6;
#pragma unroll
    for (int mp = 0; mp < MPE; ++mp) {
        float v = part[mp];
#pragma unroll
        for (int o = 32; o; o >>= 1) v += __shfl_down(v, o, 64);
        if (lane == 0) red[wid][mp] = v;
    }
    __syncthreads();
    if (tid < MPE) {
        float s = red[0][tid] + red[1][tid] + red[2][tid] + red[3][tid];
        minv[be * MPE + tid] = 1.f / (s + 1e-5f);
        ssum[tid] = s;
    }
    __syncthreads();
    if (tid == 0) {
        float es = 0.25f * (ssum[0] + ssum[1] + ssum[2] + ssum[3]);
        einv[be] = 1.f / (es + 1e-5f);
    }
}

// ---------------------------------------------------------------------------
// Kernel 2: context matmuls. 160 weight-rows per batch (32 entity + 128
// mention), 4 rows per block staged in LDS. grid = B*40, block = 256.
// Writes f32 directly into output rows 176..335 (cols 0..767).
// ---------------------------------------------------------------------------
__global__ __launch_bounds__(256) void k_ctx(
        const float* __restrict__ seq,
        const float* __restrict__ m_row, const float* __restrict__ e_row,
        const float* __restrict__ minv, const float* __restrict__ einv,
        float* __restrict__ out) {
    __shared__ float w[4][L];     // 16 KB
    int blk = blockIdx.x;
    int b = blk / 40, g = blk % 40;
    int tid = threadIdx.x;
    int orow[4];
#pragma unroll
    for (int ri = 0; ri < 4; ++ri) {
        int r = g * 4 + ri;
        const float* src; float inv;
        if (r < E) {
            src = e_row + ((size_t)b * E + r) * L;
            inv = einv[b * E + r];
            orow[ri] = NNODE + r;                 // 176 + r
        } else {
            int m = r - E;
            src = m_row + ((size_t)b * EM + m) * L;
            inv = minv[b * EM + m];
            orow[ri] = NNODE + E + m;             // 208 + m
        }
        for (int c = tid; c < L; c += 256) w[ri][c] = src[c] * inv;
    }
    __syncthreads();

    float acc[4][3] = {};
    const float* sb = seq + (size_t)b * L * H;
    for (int l = 0; l < L; ++l) {
        float w0 = w[0][l], w1 = w[1][l], w2 = w[2][l], w3 = w[3][l];
#pragma unroll
        for (int j = 0; j < 3; ++j) {
            float sv = sb[(size_t)l * H + tid + j * 256];
            acc[0][j] += w0 * sv; acc[1][j] += w1 * sv;
            acc[2][j] += w2 * sv; acc[3][j] += w3 * sv;
        }
    }
#pragma unroll
    for (int ri = 0; ri < 4; ++ri) {
        float* op = out + ((size_t)b * NROWS + orow[ri]) * F;
#pragma unroll
        for (int j = 0; j < 3; ++j)
            op[tid + j * 256] = acc[ri][j];
    }
}

// ---------------------------------------------------------------------------
// Kernel 3: link-span pooling. grid = B*K, block = 256.
// Only the span x span block of head-mean attention matters (double mask).
// Writes f32 into output rows 160..175 (cols 0..767).
// ---------------------------------------------------------------------------
__global__ __launch_bounds__(256) void k_link(
        const float* __restrict__ att,
        const float* __restrict__ seq,
        const int* __restrict__ lstart, const int* __restrict__ llen,
        float* __restrict__ out) {
    int bk = blockIdx.x;
    int b = bk >> 4, k = bk & 15;
    int s = lstart[bk] + 1;
    int len = llen[bk] + 1;         // span length in [1,31]
    int tid = threadIdx.x;
    int c = tid & 31, sub = tid >> 5;

    __shared__ float partial[8][32];
    __shared__ float wbuf[32];

    float v = 0.f;
    int pairs = len * NH;
    for (int p = sub; p < pairs; p += 8) {
        int r = s + p / NH;
        int nh = p % NH;
        v += att[(((size_t)(b * NH + nh)) * L + r) * L + (s + c)];
    }
    partial[sub][c] = v;
    __syncthreads();
    if (tid < 32) {
        float t = 0.f;
#pragma unroll
        for (int q = 0; q < 8; ++q) t += partial[q][tid];
        wbuf[tid] = t * (1.f / NH);
    }
    __syncthreads();

    const float* sb = seq + (size_t)b * L * H;
    float invlen = 1.f / (float)len;
#pragma unroll
    for (int j = 0; j < 3; ++j) {
        int h = tid + j * 256;
        float acc = 0.f;
        for (int cc = 0; cc < len; ++cc)
            acc += wbuf[cc] * sb[(size_t)(s + cc) * H + h];
        out[((size_t)b * NROWS + (E + EM + k)) * F + h] = acc * invlen;
    }
}

// ---------------------------------------------------------------------------
// Kernel 4: assembly — entity logsumexp, mention gather, type columns, zeros.
// grid = B*NROWS, block = 256.
// ---------------------------------------------------------------------------
__global__ __launch_bounds__(256) void k_assemble(
        const float* __restrict__ seq,
        const float* __restrict__ ttab,
        const int* __restrict__ mpos,
        float* __restrict__ out) {
    int blk = blockIdx.x;
    int b = blk / NROWS, r = blk % NROWS;
    int tid = threadIdx.x;
    float* orow = out + ((size_t)b * NROWS + r) * F;

    if (r < E) {
        const int* pp = mpos + (b * E + r) * MPE;
        int p0 = pp[0] + 1, p1 = pp[1] + 1, p2 = pp[2] + 1, p3 = pp[3] + 1;
        const float* sb = seq + (size_t)b * L * H;
#pragma unroll
        for (int j = 0; j < 3; ++j) {
            int h = tid + j * 256;
            float x0 = sb[(size_t)p0 * H + h];
            float x1 = sb[(size_t)p1 * H + h];
            float x2 = sb[(size_t)p2 * H + h];
            float x3 = sb[(size_t)p3 * H + h];
            float mx = fmaxf(fmaxf(x0, x1), fmaxf(x2, x3));
            float sm = expf(x0 - mx) + expf(x1 - mx) + expf(x2 - mx) + expf(x3 - mx);
            orow[h] = mx + logf(sm);
        }
        if (tid < TYPE_DIM) orow[H + tid] = ttab[0 * TYPE_DIM + tid];
    } else if (r < E + EM) {
        int m = r - E;
        int p = mpos[b * EM + m] + 1;
        const float* srow = seq + ((size_t)b * L + p) * H;
#pragma unroll
        for (int j = 0; j < 3; ++j) orow[tid + j * 256] = srow[tid + j * 256];
        if (tid < TYPE_DIM) orow[H + tid] = ttab[1 * TYPE_DIM + tid];
    } else if (r < NNODE) {
        // link row: cols 0..767 written by k_link
        if (tid < TYPE_DIM) orow[H + tid] = ttab[2 * TYPE_DIM + tid];
    } else {
        // context rows: cols 0..767 written by k_ctx; tail is zero
        if (tid < TYPE_DIM) orow[H + tid] = 0.f;
    }
}

extern "C" void kernel_launch(void* const* d_in, const int* in_sizes, int n_in,
                              void* d_out, int out_size, void* d_ws, size_t ws_size,
                              hipStream_t stream) {
    const float* seq  = (const float*)d_in[0];   // [B,L,H] f32
    const float* att  = (const float*)d_in[1];   // [B,NH,L,L] f32
    const float* ttab = (const float*)d_in[2];   // [3,20] f32
    const int* mpos   = (const int*)d_in[3];     // [B,E,MPE]
    const int* lstart = (const int*)d_in[4];     // [B,K]
    const int* llen   = (const int*)d_in[5];     // [B,K]
    float* out = (float*)d_out;                  // [B,336,788] f32

    float* m_row = (float*)d_ws;                                 // B*EM*L
    float* e_row = m_row + (size_t)B * EM * L;                   // B*E*L
    float* minv  = e_row + (size_t)B * E * L;                    // B*EM
    float* einv  = minv + (size_t)B * EM;                        // B*E

    k_rows<<<B * E, 256, 0, stream>>>(att, mpos, m_row, e_row, minv, einv);
    k_ctx<<<B * 40, 256, 0, stream>>>(seq, m_row, e_row, minv, einv, out);
    k_link<<<B * K, 256, 0, stream>>>(att, seq, lstart, llen, out);
    k_assemble<<<B * NROWS, 256, 0, stream>>>(seq, ttab, mpos, out);
}

// Round 3
// 425.995 us; speedup vs baseline: 1.0046x; 1.0046x over previous
//
#include <hip/hip_runtime.h>

constexpr int B = 4, L = 1024, H = 768, NH = 12;
constexpr int E = 32, MPE = 4, K = 16, EM = E * MPE;     // EM=128
constexpr int TYPE_DIM = 20;
constexpr int NNODE = E + EM + K;                         // 176
constexpr int NROWS = NNODE + E + EM;                     // 336
constexpr int F = H + TYPE_DIM;                           // 788

// ---------------------------------------------------------------------------
// Kernel 1: per (b, entity): head-mean attention rows for the 4 member
// mentions + entity row, PRE-SCALED by their normalizers (1/(rowsum+1e-5)).
// grid = B*E, block = 256; each thread owns 4 consecutive cols (float4).
// ---------------------------------------------------------------------------
__global__ __launch_bounds__(256) void k_rows(
        const float* __restrict__ att, const int* __restrict__ mpos,
        float* __restrict__ m_row, float* __restrict__ e_row) {
    int be = blockIdx.x;            // b*E + e
    int b = be >> 5;
    int tid = threadIdx.x;
    int c0 = tid * 4;

    int pos[MPE];
    float acc[MPE][4];
#pragma unroll
    for (int mp = 0; mp < MPE; ++mp) {
        pos[mp] = mpos[be * MPE + mp] + 1;
#pragma unroll
        for (int j = 0; j < 4; ++j) acc[mp][j] = 0.f;
    }
    for (int nh = 0; nh < NH; ++nh) {
#pragma unroll
        for (int mp = 0; mp < MPE; ++mp) {
            const float* row =
                att + (((size_t)(b * NH + nh)) * L + pos[mp]) * L + c0;
            float4 v = *(const float4*)row;
            acc[mp][0] += v.x; acc[mp][1] += v.y;
            acc[mp][2] += v.z; acc[mp][3] += v.w;
        }
    }
    // head-mean + per-mention partial row-sums
    float part[MPE];
    float er[4] = {0.f, 0.f, 0.f, 0.f};
#pragma unroll
    for (int mp = 0; mp < MPE; ++mp) {
        float s = 0.f;
#pragma unroll
        for (int j = 0; j < 4; ++j) {
            float val = acc[mp][j] * (1.f / NH);
            acc[mp][j] = val; s += val; er[j] += val;
        }
        part[mp] = s;
    }
    // block-reduce the 4 per-mention sums -> inverse normalizers in LDS
    __shared__ float red[4][4];   // [wave][mp]
    __shared__ float sinv[5];     // minv[0..3], einv
    int lane = tid & 63, wid = tid >> 6;
#pragma unroll
    for (int mp = 0; mp < MPE; ++mp) {
        float v = part[mp];
#pragma unroll
        for (int o = 32; o; o >>= 1) v += __shfl_down(v, o, 64);
        if (lane == 0) red[wid][mp] = v;
    }
    __syncthreads();
    if (tid < MPE) {
        float s = red[0][tid] + red[1][tid] + red[2][tid] + red[3][tid];
        sinv[tid] = 1.f / (s + 1e-5f);
        red[0][tid] = s;          // stash raw sum for einv
    }
    __syncthreads();
    if (tid == 0) {
        float es = 0.25f * (red[0][0] + red[0][1] + red[0][2] + red[0][3]);
        sinv[4] = 1.f / (es + 1e-5f);
    }
    __syncthreads();
    float einv = sinv[4];
#pragma unroll
    for (int mp = 0; mp < MPE; ++mp) {
        float inv = sinv[mp];
        float4 w;
        w.x = acc[mp][0] * inv; w.y = acc[mp][1] * inv;
        w.z = acc[mp][2] * inv; w.w = acc[mp][3] * inv;
        *(float4*)(m_row + ((size_t)(be * MPE + mp)) * L + c0) = w;
    }
    {
        float4 w;
        w.x = 0.25f * er[0] * einv; w.y = 0.25f * er[1] * einv;
        w.z = 0.25f * er[2] * einv; w.w = 0.25f * er[3] * einv;
        *(float4*)(e_row + (size_t)be * L + c0) = w;
    }
}

// ---------------------------------------------------------------------------
// Kernel 2: context matmul out[r,c] = sum_l w[r,l]*seq[l,c].
// grid = B * 20 row-groups * 6 col-tiles = 480 blocks, block = 128.
// 8 rows per block; w[r][l] is wave-uniform -> scalar-cache loads; seq loads
// coalesced per-thread. No LDS, no staging phase.
// ---------------------------------------------------------------------------
constexpr int RG = 8;     // rows per block
constexpr int CT = 128;   // cols per block
constexpr int NG = 160 / RG;   // 20 row groups
constexpr int NT = H / CT;     // 6 col tiles

__global__ __launch_bounds__(128) void k_ctx(
        const float* __restrict__ seq,
        const float* __restrict__ m_row, const float* __restrict__ e_row,
        float* __restrict__ out) {
    int blk = blockIdx.x;
    int b = blk / (NG * NT);
    int rem = blk % (NG * NT);
    int g = rem / NT, t = rem % NT;
    int c = t * CT + threadIdx.x;

    const float* wp[RG];
#pragma unroll
    for (int ri = 0; ri < RG; ++ri) {
        int r = g * RG + ri;
        wp[ri] = (r < E) ? e_row + ((size_t)(b * E + r)) * L
                         : m_row + ((size_t)(b * EM + (r - E))) * L;
    }
    const float* sp = seq + (size_t)b * L * H + c;

    float acc[RG] = {};
#pragma unroll 4
    for (int l = 0; l < L; ++l) {
        float sv = sp[(size_t)l * H];
#pragma unroll
        for (int ri = 0; ri < RG; ++ri)
            acc[ri] += wp[ri][l] * sv;
    }
#pragma unroll
    for (int ri = 0; ri < RG; ++ri) {
        int r = g * RG + ri;
        out[((size_t)b * NROWS + (NNODE + r)) * F + c] = acc[ri];
    }
}

// ---------------------------------------------------------------------------
// Kernel 3: link-span pooling. grid = B*K, block = 256.
// Only the span x span block of head-mean attention matters (double mask).
// ---------------------------------------------------------------------------
__global__ __launch_bounds__(256) void k_link(
        const float* __restrict__ att,
        const float* __restrict__ seq,
        const int* __restrict__ lstart, const int* __restrict__ llen,
        float* __restrict__ out) {
    int bk = blockIdx.x;
    int b = bk >> 4, k = bk & 15;
    int s = lstart[bk] + 1;
    int len = llen[bk] + 1;         // span length in [1,31]
    int tid = threadIdx.x;
    int c = tid & 31, sub = tid >> 5;

    __shared__ float partial[8][32];
    __shared__ float wbuf[32];

    float v = 0.f;
    int pairs = len * NH;
    for (int p = sub; p < pairs; p += 8) {
        int r = s + p / NH;
        int nh = p % NH;
        v += att[(((size_t)(b * NH + nh)) * L + r) * L + (s + c)];
    }
    partial[sub][c] = v;
    __syncthreads();
    if (tid < 32) {
        float t = 0.f;
#pragma unroll
        for (int q = 0; q < 8; ++q) t += partial[q][tid];
        wbuf[tid] = t * (1.f / NH);
    }
    __syncthreads();

    const float* sb = seq + (size_t)b * L * H;
    float invlen = 1.f / (float)len;
#pragma unroll
    for (int j = 0; j < 3; ++j) {
        int h = tid + j * 256;
        float acc = 0.f;
        for (int cc = 0; cc < len; ++cc)
            acc += wbuf[cc] * sb[(size_t)(s + cc) * H + h];
        out[((size_t)b * NROWS + (E + EM + k)) * F + h] = acc * invlen;
    }
}

// ---------------------------------------------------------------------------
// Kernel 4: assembly — entity logsumexp, mention gather, type columns, zeros.
// grid = B*NROWS, block = 256.
// ---------------------------------------------------------------------------
__global__ __launch_bounds__(256) void k_assemble(
        const float* __restrict__ seq,
        const float* __restrict__ ttab,
        const int* __restrict__ mpos,
        float* __restrict__ out) {
    int blk = blockIdx.x;
    int b = blk / NROWS, r = blk % NROWS;
    int tid = threadIdx.x;
    float* orow = out + ((size_t)b * NROWS + r) * F;

    if (r < E) {
        const int* pp = mpos + (b * E + r) * MPE;
        int p0 = pp[0] + 1, p1 = pp[1] + 1, p2 = pp[2] + 1, p3 = pp[3] + 1;
        const float* sb = seq + (size_t)b * L * H;
#pragma unroll
        for (int j = 0; j < 3; ++j) {
            int h = tid + j * 256;
            float x0 = sb[(size_t)p0 * H + h];
            float x1 = sb[(size_t)p1 * H + h];
            float x2 = sb[(size_t)p2 * H + h];
            float x3 = sb[(size_t)p3 * H + h];
            float mx = fmaxf(fmaxf(x0, x1), fmaxf(x2, x3));
            float sm = expf(x0 - mx) + expf(x1 - mx) + expf(x2 - mx) + expf(x3 - mx);
            orow[h] = mx + logf(sm);
        }
        if (tid < TYPE_DIM) orow[H + tid] = ttab[0 * TYPE_DIM + tid];
    } else if (r < E + EM) {
        int m = r - E;
        int p = mpos[b * EM + m] + 1;
        const float* srow = seq + ((size_t)b * L + p) * H;
#pragma unroll
        for (int j = 0; j < 3; ++j) orow[tid + j * 256] = srow[tid + j * 256];
        if (tid < TYPE_DIM) orow[H + tid] = ttab[1 * TYPE_DIM + tid];
    } else if (r < NNODE) {
        // link row: cols 0..767 written by k_link
        if (tid < TYPE_DIM) orow[H + tid] = ttab[2 * TYPE_DIM + tid];
    } else {
        // context rows: cols 0..767 written by k_ctx; tail is zero
        if (tid < TYPE_DIM) orow[H + tid] = 0.f;
    }
}

extern "C" void kernel_launch(void* const* d_in, const int* in_sizes, int n_in,
                              void* d_out, int out_size, void* d_ws, size_t ws_size,
                              hipStream_t stream) {
    const float* seq  = (const float*)d_in[0];   // [B,L,H] f32
    const float* att  = (const float*)d_in[1];   // [B,NH,L,L] f32
    const float* ttab = (const float*)d_in[2];   // [3,20] f32
    const int* mpos   = (const int*)d_in[3];     // [B,E,MPE]
    const int* lstart = (const int*)d_in[4];     // [B,K]
    const int* llen   = (const int*)d_in[5];     // [B,K]
    float* out = (float*)d_out;                  // [B,336,788] f32

    float* m_row = (float*)d_ws;                                 // B*EM*L (scaled)
    float* e_row = m_row + (size_t)B * EM * L;                   // B*E*L (scaled)

    k_rows<<<B * E, 256, 0, stream>>>(att, mpos, m_row, e_row);
    k_ctx<<<B * NG * NT, 128, 0, stream>>>(seq, m_row, e_row, out);
    k_link<<<B * K, 256, 0, stream>>>(att, seq, lstart, llen, out);
    k_assemble<<<B * NROWS, 256, 0, stream>>>(seq, ttab, mpos, out);
}

// Round 4
// 314.830 us; speedup vs baseline: 1.3593x; 1.3531x over previous
//
#include <hip/hip_runtime.h>

constexpr int B = 4, L = 1024, H = 768, NH = 12;
constexpr int E = 32, MPE = 4, K = 16, EM = E * MPE;     // EM=128
constexpr int TYPE_DIM = 20;
constexpr int NNODE = E + EM + K;                         // 176
constexpr int NROWS = NNODE + E + EM;                     // 336
constexpr int F = H + TYPE_DIM;                           // 788
constexpr int NCTX = E + EM;                              // 160 context rows

// k_ctx tiling
constexpr int KS = 4;            // K-split chunks
constexpr int KC = L / KS;       // 256 l-steps per chunk
constexpr int RG = 8;            // rows per block
constexpr int CT = 128;          // cols per block (64 threads x float2)
constexpr int NG = NCTX / RG;    // 20 row groups
constexpr int NT = H / CT;       // 6 col tiles

// ---------------------------------------------------------------------------
// Kernel 1: per (b, entity): head-mean attention rows for the 4 member
// mentions + entity row, PRE-SCALED by their normalizers (1/(rowsum+1e-5)).
// grid = B*E, block = 256; each thread owns 4 consecutive cols (float4).
// ---------------------------------------------------------------------------
__global__ __launch_bounds__(256) void k_rows(
        const float* __restrict__ att, const int* __restrict__ mpos,
        float* __restrict__ m_row, float* __restrict__ e_row) {
    int be = blockIdx.x;            // b*E + e
    int b = be >> 5;
    int tid = threadIdx.x;
    int c0 = tid * 4;

    int pos[MPE];
    float acc[MPE][4];
#pragma unroll
    for (int mp = 0; mp < MPE; ++mp) {
        pos[mp] = mpos[be * MPE + mp] + 1;
#pragma unroll
        for (int j = 0; j < 4; ++j) acc[mp][j] = 0.f;
    }
    for (int nh = 0; nh < NH; ++nh) {
#pragma unroll
        for (int mp = 0; mp < MPE; ++mp) {
            const float* row =
                att + (((size_t)(b * NH + nh)) * L + pos[mp]) * L + c0;
            float4 v = *(const float4*)row;
            acc[mp][0] += v.x; acc[mp][1] += v.y;
            acc[mp][2] += v.z; acc[mp][3] += v.w;
        }
    }
    // head-mean + per-mention partial row-sums
    float part[MPE];
    float er[4] = {0.f, 0.f, 0.f, 0.f};
#pragma unroll
    for (int mp = 0; mp < MPE; ++mp) {
        float s = 0.f;
#pragma unroll
        for (int j = 0; j < 4; ++j) {
            float val = acc[mp][j] * (1.f / NH);
            acc[mp][j] = val; s += val; er[j] += val;
        }
        part[mp] = s;
    }
    // block-reduce the 4 per-mention sums -> inverse normalizers
    __shared__ float red[4][4];   // [wave][mp]
    __shared__ float sinv[5];     // minv[0..3], einv
    int lane = tid & 63, wid = tid >> 6;
#pragma unroll
    for (int mp = 0; mp < MPE; ++mp) {
        float v = part[mp];
#pragma unroll
        for (int o = 32; o; o >>= 1) v += __shfl_down(v, o, 64);
        if (lane == 0) red[wid][mp] = v;
    }
    __syncthreads();
    if (tid < MPE) {
        float s = red[0][tid] + red[1][tid] + red[2][tid] + red[3][tid];
        sinv[tid] = 1.f / (s + 1e-5f);
        red[0][tid] = s;          // stash raw sum for einv
    }
    __syncthreads();
    if (tid == 0) {
        float es = 0.25f * (red[0][0] + red[0][1] + red[0][2] + red[0][3]);
        sinv[4] = 1.f / (es + 1e-5f);
    }
    __syncthreads();
    float einv = sinv[4];
#pragma unroll
    for (int mp = 0; mp < MPE; ++mp) {
        float inv = sinv[mp];
        float4 w;
        w.x = acc[mp][0] * inv; w.y = acc[mp][1] * inv;
        w.z = acc[mp][2] * inv; w.w = acc[mp][3] * inv;
        *(float4*)(m_row + ((size_t)(be * MPE + mp)) * L + c0) = w;
    }
    {
        float4 w;
        w.x = 0.25f * er[0] * einv; w.y = 0.25f * er[1] * einv;
        w.z = 0.25f * er[2] * einv; w.w = 0.25f * er[3] * einv;
        *(float4*)(e_row + (size_t)be * L + c0) = w;
    }
}

// ---------------------------------------------------------------------------
// Kernel 2: context matmul partials. part[kc][b][r][c] = sum over l-chunk of
// w[r][l]*seq[l][c]. grid = B*NG*NT*KS = 1920 single-wave blocks; thread owns
// 2 cols (float2) x 8 rows = 16 accs. Manual unroll-by-8: batch 8 independent
// float2 loads into regs, then FMA (one latency per 8 iters, not per 1).
// blockIdx&7 -> XCD; batch b pinned to XCD pair {2b,2b+1} for seq L2 locality.
// ---------------------------------------------------------------------------
__global__ __launch_bounds__(64) void k_ctx(
        const float* __restrict__ seq,
        const float* __restrict__ m_row, const float* __restrict__ e_row,
        float* __restrict__ part) {
    int blk = blockIdx.x;
    int xcd = blk & 7;
    int b = xcd >> 1;
    int idx = ((blk >> 3) << 1) | (xcd & 1);   // [0, 480) per batch
    int kc = idx & 3;
    int t  = (idx >> 2) % NT;
    int g  = idx / (4 * NT);
    int c = t * CT + (int)threadIdx.x * 2;

    const float* wp[RG];
#pragma unroll
    for (int ri = 0; ri < RG; ++ri) {
        int r = g * RG + ri;
        wp[ri] = ((r < E) ? e_row + ((size_t)(b * E + r)) * L
                          : m_row + ((size_t)(b * EM + (r - E))) * L) + kc * KC;
    }
    const float* sp = seq + ((size_t)b * L + kc * KC) * H + c;

    float acc[RG][2] = {};
    for (int l0 = 0; l0 < KC; l0 += 8) {
        float2 sv[8];
#pragma unroll
        for (int i = 0; i < 8; ++i)
            sv[i] = *(const float2*)(sp + (size_t)(l0 + i) * H);
#pragma unroll
        for (int i = 0; i < 8; ++i) {
#pragma unroll
            for (int ri = 0; ri < RG; ++ri) {
                float w = wp[ri][l0 + i];
                acc[ri][0] += w * sv[i].x;
                acc[ri][1] += w * sv[i].y;
            }
        }
    }
    float* pp = part + (((size_t)kc * B + b) * NCTX + g * RG) * H + c;
#pragma unroll
    for (int ri = 0; ri < RG; ++ri) {
        float2 w; w.x = acc[ri][0]; w.y = acc[ri][1];
        *(float2*)(pp + (size_t)ri * H) = w;
    }
}

// ---------------------------------------------------------------------------
// Kernel 3: link-span pooling. grid = B*K, block = 256.
// Only the span x span block of head-mean attention matters (double mask).
// ---------------------------------------------------------------------------
__global__ __launch_bounds__(256) void k_link(
        const float* __restrict__ att,
        const float* __restrict__ seq,
        const int* __restrict__ lstart, const int* __restrict__ llen,
        float* __restrict__ out) {
    int bk = blockIdx.x;
    int b = bk >> 4, k = bk & 15;
    int s = lstart[bk] + 1;
    int len = llen[bk] + 1;         // span length in [1,31]
    int tid = threadIdx.x;
    int c = tid & 31, sub = tid >> 5;

    __shared__ float partial[8][32];
    __shared__ float wbuf[32];

    float v = 0.f;
    int pairs = len * NH;
    for (int p = sub; p < pairs; p += 8) {
        int r = s + p / NH;
        int nh = p % NH;
        v += att[(((size_t)(b * NH + nh)) * L + r) * L + (s + c)];
    }
    partial[sub][c] = v;
    __syncthreads();
    if (tid < 32) {
        float t = 0.f;
#pragma unroll
        for (int q = 0; q < 8; ++q) t += partial[q][tid];
        wbuf[tid] = t * (1.f / NH);
    }
    __syncthreads();

    const float* sb = seq + (size_t)b * L * H;
    float invlen = 1.f / (float)len;
#pragma unroll
    for (int j = 0; j < 3; ++j) {
        int h = tid + j * 256;
        float acc = 0.f;
        for (int cc = 0; cc < len; ++cc)
            acc += wbuf[cc] * sb[(size_t)(s + cc) * H + h];
        out[((size_t)b * NROWS + (E + EM + k)) * F + h] = acc * invlen;
    }
}

// ---------------------------------------------------------------------------
// Kernel 4: assembly — entity logsumexp, mention gather, type columns,
// ctx-partial reduce. grid = B*NROWS, block = 256.
// ---------------------------------------------------------------------------
__global__ __launch_bounds__(256) void k_assemble(
        const float* __restrict__ seq,
        const float* __restrict__ ttab,
        const int* __restrict__ mpos,
        const float* __restrict__ part,
        float* __restrict__ out) {
    int blk = blockIdx.x;
    int b = blk / NROWS, r = blk % NROWS;
    int tid = threadIdx.x;
    float* orow = out + ((size_t)b * NROWS + r) * F;

    if (r < E) {
        const int* pp = mpos + (b * E + r) * MPE;
        int p0 = pp[0] + 1, p1 = pp[1] + 1, p2 = pp[2] + 1, p3 = pp[3] + 1;
        const float* sb = seq + (size_t)b * L * H;
#pragma unroll
        for (int j = 0; j < 3; ++j) {
            int h = tid + j * 256;
            float x0 = sb[(size_t)p0 * H + h];
            float x1 = sb[(size_t)p1 * H + h];
            float x2 = sb[(size_t)p2 * H + h];
            float x3 = sb[(size_t)p3 * H + h];
            float mx = fmaxf(fmaxf(x0, x1), fmaxf(x2, x3));
            float sm = expf(x0 - mx) + expf(x1 - mx) + expf(x2 - mx) + expf(x3 - mx);
            orow[h] = mx + logf(sm);
        }
        if (tid < TYPE_DIM) orow[H + tid] = ttab[0 * TYPE_DIM + tid];
    } else if (r < E + EM) {
        int m = r - E;
        int p = mpos[b * EM + m] + 1;
        const float* srow = seq + ((size_t)b * L + p) * H;
#pragma unroll
        for (int j = 0; j < 3; ++j) orow[tid + j * 256] = srow[tid + j * 256];
        if (tid < TYPE_DIM) orow[H + tid] = ttab[1 * TYPE_DIM + tid];
    } else if (r < NNODE) {
        // link row: cols 0..767 written by k_link
        if (tid < TYPE_DIM) orow[H + tid] = ttab[2 * TYPE_DIM + tid];
    } else {
        // ctx row: reduce the KS partials
        int rr = r - NNODE;
        const float* pp = part + ((size_t)b * NCTX + rr) * H;
#pragma unroll
        for (int j = 0; j < 3; ++j) {
            int h = tid + j * 256;
            float s = 0.f;
#pragma unroll
            for (int kc = 0; kc < KS; ++kc)
                s += pp[(size_t)kc * B * NCTX * H + h];
            orow[h] = s;
        }
        if (tid < TYPE_DIM) orow[H + tid] = 0.f;
    }
}

extern "C" void kernel_launch(void* const* d_in, const int* in_sizes, int n_in,
                              void* d_out, int out_size, void* d_ws, size_t ws_size,
                              hipStream_t stream) {
    const float* seq  = (const float*)d_in[0];   // [B,L,H] f32
    const float* att  = (const float*)d_in[1];   // [B,NH,L,L] f32
    const float* ttab = (const float*)d_in[2];   // [3,20] f32
    const int* mpos   = (const int*)d_in[3];     // [B,E,MPE]
    const int* lstart = (const int*)d_in[4];     // [B,K]
    const int* llen   = (const int*)d_in[5];     // [B,K]
    float* out = (float*)d_out;                  // [B,336,788] f32

    float* m_row = (float*)d_ws;                                 // B*EM*L (scaled)
    float* e_row = m_row + (size_t)B * EM * L;                   // B*E*L (scaled)
    float* part  = e_row + (size_t)B * E * L;                    // KS*B*160*H

    k_rows<<<B * E, 256, 0, stream>>>(att, mpos, m_row, e_row);
    k_ctx<<<B * NG * NT * KS, 64, 0, stream>>>(seq, m_row, e_row, part);
    k_link<<<B * K, 256, 0, stream>>>(att, seq, lstart, llen, out);
    k_assemble<<<B * NROWS, 256, 0, stream>>>(seq, ttab, mpos, part, out);
}

// Round 5
// 313.612 us; speedup vs baseline: 1.3646x; 1.0039x over previous
//
#include <hip/hip_runtime.h>

constexpr int B = 4, L = 1024, H = 768, NH = 12;
constexpr int E = 32, MPE = 4, K = 16, EM = E * MPE;     // EM=128
constexpr int TYPE_DIM = 20;
constexpr int NNODE = E + EM + K;                         // 176
constexpr int NROWS = NNODE + E + EM;                     // 336
constexpr int F = H + TYPE_DIM;                           // 788
constexpr int NCTX = E + EM;                              // 160 context rows

// k_ctx tiling
constexpr int KS = 4;            // K-split chunks
constexpr int KC = L / KS;       // 256 l-steps per chunk
constexpr int RG = 8;            // rows per block
constexpr int CT = 128;          // cols per block (64 threads x float2)
constexpr int NG = NCTX / RG;    // 20 row groups
constexpr int NT = H / CT;       // 6 col tiles

// ---------------------------------------------------------------------------
// Kernel 1: per (b, entity): head-mean attention rows for the 4 member
// mentions + entity row, PRE-SCALED by their normalizers (1/(rowsum+1e-5)).
// grid = B*E, block = 512 (8 waves/CU for latency hiding); each thread owns
// 2 consecutive cols (float2).
// ---------------------------------------------------------------------------
__global__ __launch_bounds__(512) void k_rows(
        const float* __restrict__ att, const int* __restrict__ mpos,
        float* __restrict__ m_row, float* __restrict__ e_row) {
    int be = blockIdx.x;            // b*E + e
    int b = be >> 5;
    int tid = threadIdx.x;
    int c0 = tid * 2;

    int pos[MPE];
    float acc[MPE][2];
#pragma unroll
    for (int mp = 0; mp < MPE; ++mp) {
        pos[mp] = mpos[be * MPE + mp] + 1;
        acc[mp][0] = 0.f; acc[mp][1] = 0.f;
    }
    for (int nh = 0; nh < NH; ++nh) {
#pragma unroll
        for (int mp = 0; mp < MPE; ++mp) {
            const float* row =
                att + (((size_t)(b * NH + nh)) * L + pos[mp]) * L + c0;
            float2 v = *(const float2*)row;
            acc[mp][0] += v.x; acc[mp][1] += v.y;
        }
    }
    // head-mean + per-mention partial row-sums
    float part[MPE];
    float er[2] = {0.f, 0.f};
#pragma unroll
    for (int mp = 0; mp < MPE; ++mp) {
        float s = 0.f;
#pragma unroll
        for (int j = 0; j < 2; ++j) {
            float val = acc[mp][j] * (1.f / NH);
            acc[mp][j] = val; s += val; er[j] += val;
        }
        part[mp] = s;
    }
    // block-reduce the 4 per-mention sums -> inverse normalizers
    __shared__ float red[8][4];   // [wave][mp]
    __shared__ float sinv[5];     // minv[0..3], einv
    int lane = tid & 63, wid = tid >> 6;
#pragma unroll
    for (int mp = 0; mp < MPE; ++mp) {
        float v = part[mp];
#pragma unroll
        for (int o = 32; o; o >>= 1) v += __shfl_down(v, o, 64);
        if (lane == 0) red[wid][mp] = v;
    }
    __syncthreads();
    if (tid < MPE) {
        float s = 0.f;
#pragma unroll
        for (int w = 0; w < 8; ++w) s += red[w][tid];
        sinv[tid] = 1.f / (s + 1e-5f);
        red[0][tid] = s;          // stash raw sum for einv
    }
    __syncthreads();
    if (tid == 0) {
        float es = 0.25f * (red[0][0] + red[0][1] + red[0][2] + red[0][3]);
        sinv[4] = 1.f / (es + 1e-5f);
    }
    __syncthreads();
    float einv = sinv[4];
#pragma unroll
    for (int mp = 0; mp < MPE; ++mp) {
        float inv = sinv[mp];
        float2 w;
        w.x = acc[mp][0] * inv; w.y = acc[mp][1] * inv;
        *(float2*)(m_row + ((size_t)(be * MPE + mp)) * L + c0) = w;
    }
    {
        float2 w;
        w.x = 0.25f * er[0] * einv; w.y = 0.25f * er[1] * einv;
        *(float2*)(e_row + (size_t)be * L + c0) = w;
    }
}

// ---------------------------------------------------------------------------
// Kernel 2: context matmul partials. part[kc][b][r][c] = sum over l-chunk of
// w[r][l]*seq[l][c]. grid = B*NG*NT*KS = 1920 single-wave blocks; thread owns
// 2 cols (float2) x 8 rows = 16 accs. Manual unroll-by-8: batch 8 independent
// float2 loads into regs, then FMA (one latency per 8 iters, not per 1).
// blockIdx&7 -> XCD; batch b pinned to XCD pair {2b,2b+1} for seq L2 locality.
// ---------------------------------------------------------------------------
__global__ __launch_bounds__(64) void k_ctx(
        const float* __restrict__ seq,
        const float* __restrict__ m_row, const float* __restrict__ e_row,
        float* __restrict__ part) {
    int blk = blockIdx.x;
    int xcd = blk & 7;
    int b = xcd >> 1;
    int idx = ((blk >> 3) << 1) | (xcd & 1);   // [0, 480) per batch
    int kc = idx & 3;
    int t  = (idx >> 2) % NT;
    int g  = idx / (4 * NT);
    int c = t * CT + (int)threadIdx.x * 2;

    const float* wp[RG];
#pragma unroll
    for (int ri = 0; ri < RG; ++ri) {
        int r = g * RG + ri;
        wp[ri] = ((r < E) ? e_row + ((size_t)(b * E + r)) * L
                          : m_row + ((size_t)(b * EM + (r - E))) * L) + kc * KC;
    }
    const float* sp = seq + ((size_t)b * L + kc * KC) * H + c;

    float acc[RG][2] = {};
    for (int l0 = 0; l0 < KC; l0 += 8) {
        float2 sv[8];
#pragma unroll
        for (int i = 0; i < 8; ++i)
            sv[i] = *(const float2*)(sp + (size_t)(l0 + i) * H);
#pragma unroll
        for (int i = 0; i < 8; ++i) {
#pragma unroll
            for (int ri = 0; ri < RG; ++ri) {
                float w = wp[ri][l0 + i];
                acc[ri][0] += w * sv[i].x;
                acc[ri][1] += w * sv[i].y;
            }
        }
    }
    float* pp = part + (((size_t)kc * B + b) * NCTX + g * RG) * H + c;
#pragma unroll
    for (int ri = 0; ri < RG; ++ri) {
        float2 w; w.x = acc[ri][0]; w.y = acc[ri][1];
        *(float2*)(pp + (size_t)ri * H) = w;
    }
}

// ---------------------------------------------------------------------------
// Kernel 3: assembly — entity logsumexp, mention gather, link-span pooling
// (fused), type columns, ctx-partial reduce. grid = B*NROWS, block = 256.
// ---------------------------------------------------------------------------
__global__ __launch_bounds__(256) void k_assemble(
        const float* __restrict__ seq,
        const float* __restrict__ att,
        const float* __restrict__ ttab,
        const int* __restrict__ mpos,
        const int* __restrict__ lstart, const int* __restrict__ llen,
        const float* __restrict__ part,
        float* __restrict__ out) {
    int blk = blockIdx.x;
    int b = blk / NROWS, r = blk % NROWS;
    int tid = threadIdx.x;
    float* orow = out + ((size_t)b * NROWS + r) * F;

    if (r < E) {
        // entity row: logsumexp over the 4 member mention embeddings
        const int* pp = mpos + (b * E + r) * MPE;
        int p0 = pp[0] + 1, p1 = pp[1] + 1, p2 = pp[2] + 1, p3 = pp[3] + 1;
        const float* sb = seq + (size_t)b * L * H;
#pragma unroll
        for (int j = 0; j < 3; ++j) {
            int h = tid + j * 256;
            float x0 = sb[(size_t)p0 * H + h];
            float x1 = sb[(size_t)p1 * H + h];
            float x2 = sb[(size_t)p2 * H + h];
            float x3 = sb[(size_t)p3 * H + h];
            float mx = fmaxf(fmaxf(x0, x1), fmaxf(x2, x3));
            float sm = expf(x0 - mx) + expf(x1 - mx) + expf(x2 - mx) + expf(x3 - mx);
            orow[h] = mx + logf(sm);
        }
        if (tid < TYPE_DIM) orow[H + tid] = ttab[0 * TYPE_DIM + tid];
    } else if (r < E + EM) {
        // mention row: token-embedding gather
        int m = r - E;
        int p = mpos[b * EM + m] + 1;
        const float* srow = seq + ((size_t)b * L + p) * H;
#pragma unroll
        for (int j = 0; j < 3; ++j) orow[tid + j * 256] = srow[tid + j * 256];
        if (tid < TYPE_DIM) orow[H + tid] = ttab[1 * TYPE_DIM + tid];
    } else if (r < NNODE) {
        // link row: span x span head-mean att pooling (fused old k_link)
        int k = r - (E + EM);
        int s = lstart[b * K + k] + 1;
        int len = llen[b * K + k] + 1;        // span length in [1,31]
        int c = tid & 31, sub = tid >> 5;

        __shared__ float partial[8][32];
        __shared__ float wbuf[32];

        float v = 0.f;
        int pairs = len * NH;
        for (int p = sub; p < pairs; p += 8) {
            int rr = s + p / NH;
            int nh = p % NH;
            v += att[(((size_t)(b * NH + nh)) * L + rr) * L + (s + c)];
        }
        partial[sub][c] = v;
        __syncthreads();
        if (tid < 32) {
            float t = 0.f;
#pragma unroll
            for (int q = 0; q < 8; ++q) t += partial[q][tid];
            wbuf[tid] = t * (1.f / NH);
        }
        __syncthreads();

        const float* sb = seq + (size_t)b * L * H;
        float invlen = 1.f / (float)len;
#pragma unroll
        for (int j = 0; j < 3; ++j) {
            int h = tid + j * 256;
            float acc = 0.f;
            for (int cc = 0; cc < len; ++cc)
                acc += wbuf[cc] * sb[(size_t)(s + cc) * H + h];
            orow[h] = acc * invlen;
        }
        if (tid < TYPE_DIM) orow[H + tid] = ttab[2 * TYPE_DIM + tid];
    } else {
        // ctx row: reduce the KS partials
        int rr = r - NNODE;
        const float* pp = part + ((size_t)b * NCTX + rr) * H;
#pragma unroll
        for (int j = 0; j < 3; ++j) {
            int h = tid + j * 256;
            float s = 0.f;
#pragma unroll
            for (int kc = 0; kc < KS; ++kc)
                s += pp[(size_t)kc * B * NCTX * H + h];
            orow[h] = s;
        }
        if (tid < TYPE_DIM) orow[H + tid] = 0.f;
    }
}

extern "C" void kernel_launch(void* const* d_in, const int* in_sizes, int n_in,
                              void* d_out, int out_size, void* d_ws, size_t ws_size,
                              hipStream_t stream) {
    const float* seq  = (const float*)d_in[0];   // [B,L,H] f32
    const float* att  = (const float*)d_in[1];   // [B,NH,L,L] f32
    const float* ttab = (const float*)d_in[2];   // [3,20] f32
    const int* mpos   = (const int*)d_in[3];     // [B,E,MPE]
    const int* lstart = (const int*)d_in[4];     // [B,K]
    const int* llen   = (const int*)d_in[5];     // [B,K]
    float* out = (float*)d_out;                  // [B,336,788] f32

    float* m_row = (float*)d_ws;                                 // B*EM*L (scaled)
    float* e_row = m_row + (size_t)B * EM * L;                   // B*E*L (scaled)
    float* part  = e_row + (size_t)B * E * L;                    // KS*B*160*H

    k_rows<<<B * E, 512, 0, stream>>>(att, mpos, m_row, e_row);
    k_ctx<<<B * NG * NT * KS, 64, 0, stream>>>(seq, m_row, e_row, part);
    k_assemble<<<B * NROWS, 256, 0, stream>>>(seq, att, ttab, mpos,
                                              lstart, llen, part, out);
}